// Round 7
// baseline (11.995 us; speedup 1.0000x reference)
//
#include <hip/hip_runtime.h>
#include <math.h>

// Problem constants (fixed by setup_inputs / module constants)
#define BS   4
#define GMAX 500
#define HW   65536           // 256*256
#define K_OFF 120            // 8*(1+2+3+4+5) raw ring offsets
#define K_PAD 64             // deduped (~61 unique) + sentinels, power of 2
#define FLAG_OFF (BS * HW * 2)
#define OFF_MAX 7241         // max |round(256*(dx+dy))| over the rings
#define TILE_SPAN 3855       // 15*256 + 15 (flat span of a 16x16 tile)

// Exact replacement for sqrtf(max(d2,0)) <= 20 (validated R6): d2 <= 400+2^-15.
#define D2_THR 0x1.900002p+8f

struct OffsetsArg { int v[K_PAD]; };   // sorted ascending, +0x40000000 sentinels

// ---------------------------------------------------------------------------
// One block = one 16x16 pixel tile of one image. 256 threads, 1 px/thread.
// grid (16,16,BS) = 1024 blocks -> 4 blocks/CU.
//   phase 1 (loop-free): 250 threads load 2 GT points each (float4);
//            wave-aggregated append (ballot + 1 atomic/wave) into LDS lists:
//            (a) disk: EXACT point-to-tile clamp distance <= 20.5 (conservative
//                margin >> f32 rounding of the reference d2 formula)
//            (b) scatter: base flat index within +-OFF_MAX of tile span
//   phase 2: per-pixel disk test, single-compare d2 threshold (R6-validated).
//   phase 3: one scatter candidate per thread (~70 active): binary lower-bound
//            into the SORTED offset table for the tile's flat window
//            [nmin-base, nmin-base+TILE_SPAN], then walk (~16 hits) with early
//            break; marks into 256-entry LDS tile mask (idempotent writes).
//   phase 4: store pixels (float2) + flag = mark ? 1 : (covered ? 0 : -1).
// ---------------------------------------------------------------------------
__global__ __launch_bounds__(256) void fused_kernel(
    const float* __restrict__ gt_points,   // (BS, GMAX, 2)
    const int*   __restrict__ gt_nums,     // (BS,)
    OffsetsArg offs,                       // sorted deduped ring offsets
    float*       __restrict__ out)         // [BS*HW*2 pixels | BS*HW flag]
{
    const int b    = blockIdx.z;
    const int tx0  = blockIdx.x << 4;           // tile origin px
    const int ty0  = blockIdx.y << 4;           // tile origin py
    const int nmin = (tx0 << 8) + ty0;          // smallest flat index in tile

    __shared__ float4 sgp[GMAX];                // (gx, gy, g2, -) disk list
    __shared__ int    sbase[GMAX];              // scatter candidate bases
    __shared__ int    offl[K_PAD];
    __shared__ unsigned char smark[256];
    __shared__ int    dcnt_, scnt_;

    const int tid  = threadIdx.x;
    const int lane = tid & 63;
    if (tid == 0) { dcnt_ = 0; scnt_ = 0; }
    smark[tid] = 0;
    if (tid < K_PAD) offl[tid] = offs.v[tid];
    __syncthreads();                             // counters zeroed before atomics

    // ---- phase 1: candidate build, loop-free, wave-aggregated appends ----
    const int num = gt_nums[b];
    const float txl = (float)tx0, txh = (float)(tx0 + 15);
    const float tyl = (float)ty0, tyh = (float)(ty0 + 15);
    const int   blo = nmin - OFF_MAX, bhi = nmin + TILE_SPAN + OFF_MAX;

    bool dc0 = false, dc1 = false, sc0 = false, sc1 = false;
    float gx0 = 0.f, gy0 = 0.f, gx1 = 0.f, gy1 = 0.f;
    int base0 = 0, base1 = 0;
    if (tid < 250) {                             // 250*2 = 500 = GMAX, no OOB
        const float4 q = ((const float4*)gt_points)[b * (GMAX / 2) + tid];
        gx0 = q.x; gy0 = q.y; gx1 = q.z; gy1 = q.w;
        const bool v0 = (2 * tid)     < num;
        const bool v1 = (2 * tid + 1) < num;
        // exact disk-tile intersection cull: clamp-based point-to-box distance
        const float cx0 = fmaxf(fmaxf(txl - gx0, gx0 - txh), 0.0f);
        const float cy0 = fmaxf(fmaxf(tyl - gy0, gy0 - tyh), 0.0f);
        const float cx1 = fmaxf(fmaxf(txl - gx1, gx1 - txh), 0.0f);
        const float cy1 = fmaxf(fmaxf(tyl - gy1, gy1 - tyh), 0.0f);
        dc0 = v0 & (cx0 * cx0 + cy0 * cy0 <= 420.25f);   // (20.5)^2
        dc1 = v1 & (cx1 * cx1 + cy1 * cy1 <= 420.25f);
        // validated base formula: x*256, y*256 exact, one rounded add, rint
        base0 = (int)rintf(__fadd_rn(__fmul_rn(gx0, 256.0f),
                                     __fmul_rn(gy0, 256.0f)));
        base1 = (int)rintf(__fadd_rn(__fmul_rn(gx1, 256.0f),
                                     __fmul_rn(gy1, 256.0f)));
        sc0 = v0 & (base0 >= blo) & (base0 <= bhi);
        sc1 = v1 & (base1 >= blo) & (base1 <= bhi);
    }

#define APPEND_DISK(cond, gx, gy)                                            \
    {                                                                        \
        const unsigned long long m = __ballot(cond);                         \
        if (m) {                                                             \
            const int ldr = __builtin_ctzll(m);                              \
            int pos0 = 0;                                                    \
            if (lane == ldr) pos0 = atomicAdd(&dcnt_, __popcll(m));          \
            pos0 = __shfl(pos0, ldr);                                        \
            if (cond) {                                                      \
                const float g2 = __fadd_rn(__fmul_rn(gx, gx),                \
                                           __fmul_rn(gy, gy));               \
                sgp[pos0 + __popcll(m & ((1ull << lane) - 1))] =             \
                    make_float4(gx, gy, g2, 0.0f);                           \
            }                                                                \
        }                                                                    \
    }
#define APPEND_SCAT(cond, base)                                              \
    {                                                                        \
        const unsigned long long m = __ballot(cond);                         \
        if (m) {                                                             \
            const int ldr = __builtin_ctzll(m);                              \
            int pos0 = 0;                                                    \
            if (lane == ldr) pos0 = atomicAdd(&scnt_, __popcll(m));          \
            pos0 = __shfl(pos0, ldr);                                        \
            if (cond)                                                        \
                sbase[pos0 + __popcll(m & ((1ull << lane) - 1))] = base;     \
        }                                                                    \
    }

    APPEND_DISK(dc0, gx0, gy0)
    APPEND_DISK(dc1, gx1, gy1)
    APPEND_SCAT(sc0, base0)
    APPEND_SCAT(sc1, base1)
    __syncthreads();

    // ---- phase 2: per-pixel disk coverage (exact rounded formula) ----
    const int pxi = tx0 + (tid >> 4), pyi = ty0 + (tid & 15);
    const float px = (float)pxi, py = (float)pyi;
    const float p2 = px * px + py * py;          // exact (ints < 2^24)

    bool found = false;
    const int dcnt = dcnt_;
#pragma unroll 4
    for (int i = 0; i < dcnt; ++i) {
        const float4 gp = sgp[i];                // broadcast ds_read_b128
        const float cross = __fadd_rn(__fmul_rn(px, gp.x),
                                      __fmul_rn(py, gp.y));
        const float d2 = __fsub_rn(__fadd_rn(p2, gp.z),
                                   __fmul_rn(2.0f, cross));
        found |= (d2 <= D2_THR);
    }

    // ---- phase 3: one candidate per thread; sorted-window walk ----
    const int scnt = scnt_;
    for (int s = tid; s < scnt; s += 256) {
        const int bse = sbase[s];
        const int lo  = nmin - bse;              // offsets in [lo, lo+TILE_SPAN]
        const int hi  = lo + TILE_SPAN;
        int j = 0;                               // lower_bound(offl, lo), 6 steps
#pragma unroll
        for (int step = 32; step; step >>= 1)
            if (offl[j + step - 1] < lo) j += step;
        for (; j < K_PAD; ++j) {
            const int o = offl[j];
            if (o > hi) break;                   // sentinels (+2^30) stop walk
            const unsigned local = (unsigned)(bse + o - nmin); // in [0,TILE_SPAN]
            if ((local & 255u) < 16u)
                smark[((local >> 8) << 4) | (local & 15u)] = 1;
        }
    }
    __syncthreads();

    // ---- phase 4: stores; priority scatter(+1) > covered(0) > negative(-1) ----
    const int n = (pxi << 8) | pyi;
    ((float2*)out)[b * HW + n] = make_float2(px, py);
    out[FLAG_OFF + b * HW + n] = smark[tid] ? 1.0f : (found ? 0.0f : -1.0f);
}

extern "C" void kernel_launch(void* const* d_in, const int* in_sizes, int n_in,
                              void* d_out, int out_size, void* d_ws, size_t ws_size,
                              hipStream_t stream) {
    // inputs: [0] images (unused), [1] gt_points, [2] gt_nums
    const float* gt_points = (const float*)d_in[1];
    const int*   gt_nums   = (const int*)d_in[2];
    float* out = (float*)d_out;

    // Ring offsets: host double trig (libm, matches numpy), half-even rint,
    // dedup (marking idempotent), sort ascending, pad with +2^30 sentinels.
    OffsetsArg offs;
    {
        int raw[K_OFF];
        int k = 0;
        for (int i = 0; i < 5; ++i) {
            const int    nn = 8 * (i + 1);
            const double r  = 4.0 * (i + 1);
            for (int j = 0; j < nn; ++j) {
                const double ang = (double)j / (double)nn * 2.0 * M_PI;
                raw[k++] = (int)rint(r * sin(ang) * 256.0 +
                                     r * cos(ang) * 256.0);
            }
        }
        int u = 0;
        for (int a = 0; a < K_OFF; ++a) {
            bool seen = false;
            for (int q = 0; q < u; ++q)
                if (offs.v[q] == raw[a]) { seen = true; break; }
            if (!seen && u < K_PAD) offs.v[u++] = raw[a];
        }
        for (int a = 0; a < u; ++a)              // insertion sort (tiny)
            for (int q = a + 1; q < u; ++q)
                if (offs.v[q] < offs.v[a]) {
                    const int t = offs.v[a]; offs.v[a] = offs.v[q]; offs.v[q] = t;
                }
        for (; u < K_PAD; ++u) offs.v[u] = 0x40000000;  // +sentinel: > any hi
    }

    fused_kernel<<<dim3(16, 16, BS), 256, 0, stream>>>(gt_points, gt_nums, offs, out);
}

// Round 8
// 10.738 us; speedup vs baseline: 1.1170x; 1.1170x over previous
//
#include <hip/hip_runtime.h>
#include <math.h>

// Problem constants (fixed by setup_inputs / module constants)
#define BS   4
#define GMAX 500
#define HW   65536           // 256*256
#define K_OFF 120            // 8*(1+2+3+4+5) raw ring offsets
#define K_PAD 64             // deduped (~61 unique) + sentinels = wave size
#define FLAG_OFF (BS * HW * 2)
#define OFF_MAX 7241         // max |round(256*(dx+dy))| over the rings
#define TILE_SPAN 3855       // 15*256 + 15 (flat span of a 16x16 tile)

// Exact replacement for sqrtf(max(d2,0)) <= 20 (validated R6): d2 <= 400+2^-15.
#define D2_THR 0x1.900002p+8f

struct OffsetsArg { int v[K_PAD]; };

// ---------------------------------------------------------------------------
// One block = one 16x16 pixel tile of one image. 256 threads, 1 px/thread.
// grid (16,16,BS) = 1024 blocks -> 4 blocks/CU.
//   phase 1 (loop-free): 250 threads load 2 GT points each (float4);
//            wave-aggregated append (ballot + 1 atomic/wave) into LDS lists:
//            (a) disk: exact clamp point-to-tile distance <= 20.5
//                (0.5 px margin >> f32 rounding of the reference d2 formula)
//            (b) scatter: base flat index within +-OFF_MAX of tile span
//   phase 2: per-pixel disk test, single-compare d2 threshold (R6-validated).
//   phase 3 (throughput form, R7 post-mortem): lane owns offset offl[lane]
//            (hoisted, loop-invariant); wave w handles candidates s = w, w+4,…
//            -> sbase[s] is a wave-uniform broadcast LDS read; ~6 instr/iter,
//            all iterations independent (no serial LDS chains, no divergence).
//   phase 4: store pixels (float2) + flag = mark ? 1 : (covered ? 0 : -1).
// ---------------------------------------------------------------------------
__global__ __launch_bounds__(256) void fused_kernel(
    const float* __restrict__ gt_points,   // (BS, GMAX, 2)
    const int*   __restrict__ gt_nums,     // (BS,)
    OffsetsArg offs,                       // deduped ring offsets + sentinels
    float*       __restrict__ out)         // [BS*HW*2 pixels | BS*HW flag]
{
    const int b    = blockIdx.z;
    const int tx0  = blockIdx.x << 4;           // tile origin px
    const int ty0  = blockIdx.y << 4;           // tile origin py
    const int nmin = (tx0 << 8) + ty0;          // smallest flat index in tile

    __shared__ float4 sgp[GMAX];                // (gx, gy, g2, -) disk list
    __shared__ int    sbase[GMAX];              // scatter candidate bases
    __shared__ int    offl[K_PAD];
    __shared__ unsigned char smark[256];
    __shared__ int    dcnt_, scnt_;

    const int tid  = threadIdx.x;
    const int lane = tid & 63;
    if (tid == 0) { dcnt_ = 0; scnt_ = 0; }
    smark[tid] = 0;
    if (tid < K_PAD) offl[tid] = offs.v[tid];
    __syncthreads();                             // counters zeroed before atomics

    // ---- phase 1: candidate build, loop-free, wave-aggregated appends ----
    const int num = gt_nums[b];
    const float txl = (float)tx0, txh = (float)(tx0 + 15);
    const float tyl = (float)ty0, tyh = (float)(ty0 + 15);
    const int   blo = nmin - OFF_MAX, bhi = nmin + TILE_SPAN + OFF_MAX;

    bool dc0 = false, dc1 = false, sc0 = false, sc1 = false;
    float gx0 = 0.f, gy0 = 0.f, gx1 = 0.f, gy1 = 0.f;
    int base0 = 0, base1 = 0;
    if (tid < 250) {                             // 250*2 = 500 = GMAX, no OOB
        const float4 q = ((const float4*)gt_points)[b * (GMAX / 2) + tid];
        gx0 = q.x; gy0 = q.y; gx1 = q.z; gy1 = q.w;
        const bool v0 = (2 * tid)     < num;
        const bool v1 = (2 * tid + 1) < num;
        // exact disk-tile intersection cull: clamp-based point-to-box distance
        const float cx0 = fmaxf(fmaxf(txl - gx0, gx0 - txh), 0.0f);
        const float cy0 = fmaxf(fmaxf(tyl - gy0, gy0 - tyh), 0.0f);
        const float cx1 = fmaxf(fmaxf(txl - gx1, gx1 - txh), 0.0f);
        const float cy1 = fmaxf(fmaxf(tyl - gy1, gy1 - tyh), 0.0f);
        dc0 = v0 & (cx0 * cx0 + cy0 * cy0 <= 420.25f);   // (20.5)^2
        dc1 = v1 & (cx1 * cx1 + cy1 * cy1 <= 420.25f);
        // validated base formula: x*256, y*256 exact, one rounded add, rint
        base0 = (int)rintf(__fadd_rn(__fmul_rn(gx0, 256.0f),
                                     __fmul_rn(gy0, 256.0f)));
        base1 = (int)rintf(__fadd_rn(__fmul_rn(gx1, 256.0f),
                                     __fmul_rn(gy1, 256.0f)));
        sc0 = v0 & (base0 >= blo) & (base0 <= bhi);
        sc1 = v1 & (base1 >= blo) & (base1 <= bhi);
    }

#define APPEND_DISK(cond, gx, gy)                                            \
    {                                                                        \
        const unsigned long long m = __ballot(cond);                         \
        if (m) {                                                             \
            const int ldr = __builtin_ctzll(m);                              \
            int pos0 = 0;                                                    \
            if (lane == ldr) pos0 = atomicAdd(&dcnt_, __popcll(m));          \
            pos0 = __shfl(pos0, ldr);                                        \
            if (cond) {                                                      \
                const float g2 = __fadd_rn(__fmul_rn(gx, gx),                \
                                           __fmul_rn(gy, gy));               \
                sgp[pos0 + __popcll(m & ((1ull << lane) - 1))] =             \
                    make_float4(gx, gy, g2, 0.0f);                           \
            }                                                                \
        }                                                                    \
    }
#define APPEND_SCAT(cond, base)                                              \
    {                                                                        \
        const unsigned long long m = __ballot(cond);                         \
        if (m) {                                                             \
            const int ldr = __builtin_ctzll(m);                              \
            int pos0 = 0;                                                    \
            if (lane == ldr) pos0 = atomicAdd(&scnt_, __popcll(m));          \
            pos0 = __shfl(pos0, ldr);                                        \
            if (cond)                                                        \
                sbase[pos0 + __popcll(m & ((1ull << lane) - 1))] = base;     \
        }                                                                    \
    }

    APPEND_DISK(dc0, gx0, gy0)
    APPEND_DISK(dc1, gx1, gy1)
    APPEND_SCAT(sc0, base0)
    APPEND_SCAT(sc1, base1)
    __syncthreads();

    // ---- phase 2: per-pixel disk coverage (exact rounded formula) ----
    const int pxi = tx0 + (tid >> 4), pyi = ty0 + (tid & 15);
    const float px = (float)pxi, py = (float)pyi;
    const float p2 = px * px + py * py;          // exact (ints < 2^24)

    bool found = false;
    const int dcnt = dcnt_;
#pragma unroll 4
    for (int i = 0; i < dcnt; ++i) {
        const float4 gp = sgp[i];                // broadcast ds_read_b128
        const float cross = __fadd_rn(__fmul_rn(px, gp.x),
                                      __fmul_rn(py, gp.y));
        const float d2 = __fsub_rn(__fadd_rn(p2, gp.z),
                                   __fmul_rn(2.0f, cross));
        found |= (d2 <= D2_THR);
    }

    // ---- phase 3: throughput scatter-mark; lane owns one offset ----
    const int wid   = tid >> 6;                  // wave id 0..3
    const int myoff = offl[lane] - nmin;         // loop-invariant (1 LDS read)
    const int scnt  = scnt_;
    for (int s = wid; s < scnt; s += 4) {
        const unsigned local = (unsigned)(sbase[s] + myoff);  // bcast LDS read
        if (local <= (unsigned)TILE_SPAN && (local & 255u) < 16u)
            smark[((local >> 8) << 4) | (local & 15u)] = 1;
    }
    __syncthreads();

    // ---- phase 4: stores; priority scatter(+1) > covered(0) > negative(-1) ----
    const int n = (pxi << 8) | pyi;
    ((float2*)out)[b * HW + n] = make_float2(px, py);
    out[FLAG_OFF + b * HW + n] = smark[tid] ? 1.0f : (found ? 0.0f : -1.0f);
}

extern "C" void kernel_launch(void* const* d_in, const int* in_sizes, int n_in,
                              void* d_out, int out_size, void* d_ws, size_t ws_size,
                              hipStream_t stream) {
    // inputs: [0] images (unused), [1] gt_points, [2] gt_nums
    const float* gt_points = (const float*)d_in[1];
    const int*   gt_nums   = (const int*)d_in[2];
    float* out = (float*)d_out;

    // Ring offsets: host double trig (libm, matches numpy), half-even rint,
    // then dedup (marking is idempotent -> duplicates are redundant).
    OffsetsArg offs;
    {
        int raw[K_OFF];
        int k = 0;
        for (int i = 0; i < 5; ++i) {
            const int    nn = 8 * (i + 1);
            const double r  = 4.0 * (i + 1);
            for (int j = 0; j < nn; ++j) {
                const double ang = (double)j / (double)nn * 2.0 * M_PI;
                raw[k++] = (int)rint(r * sin(ang) * 256.0 +
                                     r * cos(ang) * 256.0);
            }
        }
        int u = 0;
        for (int a = 0; a < K_OFF; ++a) {
            bool seen = false;
            for (int q = 0; q < u; ++q)
                if (offs.v[q] == raw[a]) { seen = true; break; }
            if (!seen && u < K_PAD) offs.v[u++] = raw[a];
        }
        // ~61 unique expected; sentinel offsets can never land in-tile
        // (bse - nmin in [-OFF_MAX, SPAN+OFF_MAX]; -2^30 wraps to huge unsigned)
        for (; u < K_PAD; ++u) offs.v[u] = -0x40000000;
    }

    fused_kernel<<<dim3(16, 16, BS), 256, 0, stream>>>(gt_points, gt_nums, offs, out);
}